// Round 10
// baseline (343.060 us; speedup 1.0000x reference)
//
#include <hip/hip_runtime.h>
#include <hip/hip_bf16.h>
#include <math.h>

// GAT 3-layer forward for MI355X.
// R9: quarter-per-node aggregation (16 lanes = 64 cols own one node) ->
// 4 independent gather chains/wave with ~1/4 the registers of R8's
// interleave, zero cross-lane reduction (den complete per lane), and a
// depth-2 software pipeline on the csr->asb/h gather chain. CSR build
// switched to no-atomic per-chunk hist + 1-block colscan (R5-validated).
// Structure: 4 CSR dispatches, gemm0, [agg+gemm] x2 fused, agg_final.

#define NEG_SLOPE 0.2f
#define L1_CHUNK 4096

// ---------------- two-level CSR build ----------------

// per-chunk 256-bucket histogram (bucket = dst>>8); no global atomics
__global__ __launch_bounds__(256) void k_l1hist(
    const int* __restrict__ idx, int* __restrict__ bh, int E, int etot) {
    __shared__ int h[256];
    const int t = threadIdx.x;
    h[t] = 0;
    __syncthreads();
    const int base = blockIdx.x * L1_CHUNK;
    for (int i = t; i < L1_CHUNK; i += 256) {
        int e = base + i;
        if (e >= etot) break;
        int dst = (e < E) ? idx[E + e] : (e - E);
        atomicAdd(&h[dst >> 8], 1);
    }
    __syncthreads();
    bh[blockIdx.x * 256 + t] = h[t];
}

// one block: bucket offsets goff[257] + per-chunk running cursors base[][]
__global__ __launch_bounds__(256) void k_colscan(
    const int* __restrict__ bh, int* __restrict__ base,
    int* __restrict__ goff, int nchunk) {
    __shared__ int sc[256];
    const int t = threadIdx.x;
    int tot = 0;
    for (int r = 0; r < nchunk; ++r) tot += bh[r * 256 + t];
    sc[t] = tot;
    __syncthreads();
    for (int o = 1; o < 256; o <<= 1) {
        int v = (t >= o) ? sc[t - o] : 0;
        __syncthreads();
        sc[t] += v;
        __syncthreads();
    }
    int run = sc[t] - tot;   // exclusive
    goff[t] = run;
    if (t == 255) goff[256] = sc[255];
    for (int r = 0; r < nchunk; ++r) {
        base[r * 256 + t] = run;
        run += bh[r * 256 + t];
    }
}

// scatter packed (dst,src) into bucket-contiguous buf (LDS cursors only)
__global__ __launch_bounds__(256) void k_l1scatter(
    const int* __restrict__ idx, const int* __restrict__ base,
    unsigned long long* __restrict__ buf, int E, int etot) {
    __shared__ int cur[256];
    const int t = threadIdx.x;
    cur[t] = base[blockIdx.x * 256 + t];
    __syncthreads();
    const int cb = blockIdx.x * L1_CHUNK;
    for (int i = t; i < L1_CHUNK; i += 256) {
        int e = cb + i;
        if (e >= etot) break;
        int dst, src;
        if (e < E) { dst = idx[E + e]; src = idx[e]; }
        else       { dst = src = e - E; }
        int pos = atomicAdd(&cur[dst >> 8], 1);
        buf[pos] = ((unsigned long long)(unsigned)dst << 32) | (unsigned)src;
    }
}

// per-bucket exact-dst counting sort -> off[], csr[]
__global__ __launch_bounds__(256) void k_l2build(
    const unsigned long long* __restrict__ buf, const int* __restrict__ goff,
    int* __restrict__ off, int* __restrict__ csr, int n, int etot) {
    __shared__ int sc[256];
    __shared__ int lcur[256];
    const int b = blockIdx.x, t = threadIdx.x;
    const int lo = goff[b], hi = goff[b + 1];
    sc[t] = 0;
    __syncthreads();
    for (int p = lo + t; p < hi; p += 256) {
        int dst = (int)(buf[p] >> 32);
        atomicAdd(&sc[dst & 255], 1);
    }
    __syncthreads();
    int v = sc[t];
    __syncthreads();
    sc[t] = v;
    __syncthreads();
    for (int o = 1; o < 256; o <<= 1) {
        int x = (t >= o) ? sc[t - o] : 0;
        __syncthreads();
        sc[t] += x;
        __syncthreads();
    }
    int excl = sc[t] - v;
    const int d = b * 256 + t;
    if (d < n) off[d] = lo + excl;
    lcur[t] = lo + excl;
    __syncthreads();
    for (int p = lo + t; p < hi; p += 256) {
        unsigned long long e = buf[p];
        int dst = (int)(e >> 32);
        int src = (int)(e & 0xffffffffu);
        int pos = atomicAdd(&lcur[dst & 255], 1);
        csr[pos] = src;
    }
    if (b == 0 && t == 0) off[n] = etot;
}

// ---------------- compute ----------------

// Quarter-per-node aggregate: the calling quarter's 16 lanes own all 64
// cols of `node` (lane c4 -> cols 4c4..4c4+3). Edge list walked serially
// with a depth-2 software pipeline (csr at p+2, asb/h at p+1 in flight).
// den needs no reduction: each lane's 4 cols share one head.
// Returns averaged result valid on ALL 16 lanes of the quarter.
template <int H>
__device__ __forceinline__ float4 aggq(
    const float* __restrict__ h, const float* __restrict__ asb,
    const float* __restrict__ adb, const int* __restrict__ off,
    const int* __restrict__ csr, int node, int c4, int n) {
    const int head = (H == 1) ? 0 : (c4 >> 2);
    float den = 0.f;
    float4 acc = make_float4(0.f, 0.f, 0.f, 0.f);
    int p = 0, e = 0;
    float adn = 0.f;
    if (node < n) {
        p = off[node];
        e = off[node + 1];
        adn = adb[node * H + head];
    }
    // prologue: stage 0 and 1
    int s0 = csr[p < e ? p : 0];
    int s1 = csr[(p + 1) < e ? (p + 1) : 0];
    float as0 = asb[s0 * H + head];
    float4 hv0 = *(const float4*)(h + (size_t)s0 * 64 + c4 * 4);
    while (__any(p < e)) {
        const bool valid = p < e;
        const int p2 = p + 2;
        const int s2 = csr[p2 < e ? p2 : 0];           // stage p+2 index
        const float as1 = asb[s1 * H + head];          // stage p+1 logits
        const float4 hv1 = *(const float4*)(h + (size_t)s1 * 64 + c4 * 4);
        float ev = as0 + adn;                          // consume stage p
        ev = ev > 0.f ? ev : NEG_SLOPE * ev;
        const float wv = valid ? __expf(ev) : 0.f;
        den += wv;
        acc.x = fmaf(wv, hv0.x, acc.x);
        acc.y = fmaf(wv, hv0.y, acc.y);
        acc.z = fmaf(wv, hv0.z, acc.z);
        acc.w = fmaf(wv, hv0.w, acc.w);
        p = p + 1;
        s0 = s1; s1 = s2; as0 = as1; hv0 = hv1;
    }
    const float inv = 1.f / (den + 1e-16f);
    return make_float4(acc.x * inv, acc.y * inv, acc.z * inv, acc.w * inv);
}

// Layer-0 GEMM: h = x @ W (K=128) + logits. Block = 16 nodes, wave = 4.
template <int K, int H, int F>
__global__ __launch_bounds__(256) void k_gemm_alpha(
    const float* __restrict__ x, const float* __restrict__ W,
    const float* __restrict__ a_s, const float* __restrict__ a_d,
    float* __restrict__ h, float* __restrict__ as_o, float* __restrict__ ad_o,
    int n) {
    __shared__ float xs[16][K];
    const int tid = threadIdx.x;
    const int base = blockIdx.x * 16;
    int rows = n - base; if (rows > 16) rows = 16;
    const int kv = K / 4;
    for (int i = tid; i < rows * kv; i += 256) {
        int r = i / kv, c = i - r * kv;
        ((float4*)&xs[r][0])[c] = ((const float4*)(x + (size_t)(base + r) * K))[c];
    }
    __syncthreads();
    const int w = tid >> 6, lane = tid & 63;
    const int node0 = base + w * 4;
    float acc0 = 0.f, acc1 = 0.f, acc2 = 0.f, acc3 = 0.f;
    #pragma unroll 4
    for (int k = 0; k < K; ++k) {
        float wv = W[k * 64 + lane];
        acc0 = fmaf(xs[w * 4 + 0][k], wv, acc0);
        acc1 = fmaf(xs[w * 4 + 1][k], wv, acc1);
        acc2 = fmaf(xs[w * 4 + 2][k], wv, acc2);
        acc3 = fmaf(xs[w * 4 + 3][k], wv, acc3);
    }
    const int head = (H == 1) ? 0 : (lane >> 4);
    const int f = (H == 1) ? lane : (lane & (F - 1));
    const float asv = a_s[head * F + f];
    const float adv = a_d[head * F + f];
    float accs[4] = {acc0, acc1, acc2, acc3};
    #pragma unroll
    for (int j = 0; j < 4; ++j) {
        int node = node0 + j;
        if (node >= n) break;
        h[(size_t)node * 64 + lane] = accs[j];
        float vs = accs[j] * asv;
        float vd = accs[j] * adv;
        #pragma unroll
        for (int o = F >> 1; o > 0; o >>= 1) {
            vs += __shfl_xor(vs, o);
            vd += __shfl_xor(vd, o);
        }
        if (f == 0) {
            as_o[node * H + head] = vs;
            ad_o[node * H + head] = vd;
        }
    }
}

// Fused agg(layer l) -> +bias -> ELU -> gemm(layer l+1) + logits.
// Quarter q of wave w aggregates node base + w*4 + q into LDS row w*4+q.
template <int HA, int HG, int FG>
__global__ __launch_bounds__(256) void k_agg_gemm(
    const float* __restrict__ h_in, const float* __restrict__ asb_in,
    const float* __restrict__ adb_in, const int* __restrict__ off,
    const int* __restrict__ csr, const float* __restrict__ bias,
    const float* __restrict__ W, const float* __restrict__ a_s,
    const float* __restrict__ a_d, float* __restrict__ h_out,
    float* __restrict__ asb_out, float* __restrict__ adb_out, int n) {
    __shared__ float xs[16][64];
    const int tid = threadIdx.x;
    const int w = tid >> 6, lane = tid & 63;
    const int q = lane >> 4, c4 = lane & 15;
    const int base = blockIdx.x * 16;
    const int nodeA = base + w * 4 + q;
    float4 r = aggq<HA>(h_in, asb_in, adb_in, off, csr, nodeA, c4, n);
    if (nodeA < n) {
        const float4 bv = *(const float4*)(bias + c4 * 4);
        r.x += bv.x; r.y += bv.y; r.z += bv.z; r.w += bv.w;
        r.x = r.x > 0.f ? r.x : expm1f(r.x);
        r.y = r.y > 0.f ? r.y : expm1f(r.y);
        r.z = r.z > 0.f ? r.z : expm1f(r.z);
        r.w = r.w > 0.f ? r.w : expm1f(r.w);
        *(float4*)&xs[w * 4 + q][c4 * 4] = r;
    }
    __syncthreads();
    float acc0 = 0.f, acc1 = 0.f, acc2 = 0.f, acc3 = 0.f;
    #pragma unroll 4
    for (int k = 0; k < 64; ++k) {
        float wv = W[k * 64 + lane];
        acc0 = fmaf(xs[w * 4 + 0][k], wv, acc0);
        acc1 = fmaf(xs[w * 4 + 1][k], wv, acc1);
        acc2 = fmaf(xs[w * 4 + 2][k], wv, acc2);
        acc3 = fmaf(xs[w * 4 + 3][k], wv, acc3);
    }
    const int head = (HG == 1) ? 0 : (lane >> 4);
    const int f = (HG == 1) ? lane : (lane & (FG - 1));
    const float asv = a_s[head * FG + f];
    const float adv = a_d[head * FG + f];
    float accs[4] = {acc0, acc1, acc2, acc3};
    const int node0 = base + w * 4;
    #pragma unroll
    for (int j = 0; j < 4; ++j) {
        int node = node0 + j;
        if (node >= n) break;
        h_out[(size_t)node * 64 + lane] = accs[j];
        float vs = accs[j] * asv;
        float vd = accs[j] * adv;
        #pragma unroll
        for (int o = FG >> 1; o > 0; o >>= 1) {
            vs += __shfl_xor(vs, o);
            vd += __shfl_xor(vd, o);
        }
        if (f == 0) {
            asb_out[node * HG + head] = vs;
            adb_out[node * HG + head] = vd;
        }
    }
}

// Final aggregate (layer 2, H=1, no ELU) -> d_out. Quarter per node.
__global__ __launch_bounds__(256) void k_agg_final(
    const float* __restrict__ h, const float* __restrict__ asb,
    const float* __restrict__ adb, const int* __restrict__ off,
    const int* __restrict__ csr, const float* __restrict__ bias,
    float* __restrict__ out, int n) {
    const int tid = threadIdx.x;
    const int w = tid >> 6, lane = tid & 63;
    const int q = lane >> 4, c4 = lane & 15;
    const int node = blockIdx.x * 16 + w * 4 + q;
    float4 r = aggq<1>(h, asb, adb, off, csr, node, c4, n);
    if (node < n) {
        const float4 bv = *(const float4*)(bias + c4 * 4);
        r.x += bv.x; r.y += bv.y; r.z += bv.z; r.w += bv.w;
        *(float4*)(out + (size_t)node * 64 + c4 * 4) = r;
    }
}

// ---------------- launch ----------------

extern "C" void kernel_launch(void* const* d_in, const int* in_sizes, int n_in,
                              void* d_out, int out_size, void* d_ws, size_t ws_size,
                              hipStream_t stream) {
    const float* x   = (const float*)d_in[0];
    const int*   idx = (const int*)d_in[1];
    const float* W0  = (const float*)d_in[2];
    const float* as0 = (const float*)d_in[3];
    const float* ad0 = (const float*)d_in[4];
    const float* b0  = (const float*)d_in[5];
    const float* W1  = (const float*)d_in[6];
    const float* as1 = (const float*)d_in[7];
    const float* ad1 = (const float*)d_in[8];
    const float* b1  = (const float*)d_in[9];
    const float* W2  = (const float*)d_in[10];
    const float* as2 = (const float*)d_in[11];
    const float* ad2 = (const float*)d_in[12];
    const float* b2  = (const float*)d_in[13];
    float* out = (float*)d_out;

    const int n    = in_sizes[0] / 128;   // 50000
    const int E    = in_sizes[1] / 2;     // 800000
    const int etot = E + n;

    char* p = (char*)d_ws;
    auto alloc = [&](size_t bytes) {
        char* r = p;
        p += (bytes + 255) & ~(size_t)255;
        return r;
    };
    const int nb_l1 = (etot + L1_CHUNK - 1) / L1_CHUNK;  // 208
    int*   off  = (int*)alloc((size_t)(n + 1) * 4);
    int*   csr  = (int*)alloc((size_t)etot * 4);
    int*   bh   = (int*)alloc((size_t)nb_l1 * 256 * 4);
    int*   base = (int*)alloc((size_t)nb_l1 * 256 * 4);
    int*   goff = (int*)alloc(257 * 4);
    float* asbA = (float*)alloc((size_t)n * 4 * 4);
    float* adbA = (float*)alloc((size_t)n * 4 * 4);
    float* asbB = (float*)alloc((size_t)n * 4 * 4);
    float* adbB = (float*)alloc((size_t)n * 4 * 4);
    float* hA   = (float*)alloc((size_t)n * 64 * 4);
    float* hB   = (float*)alloc((size_t)n * 64 * 4);
    // buf (etot*8 = 6.8 MB) aliases hB: buf dead after k_l2build, hB first
    // written by the first k_agg_gemm (later in stream order).
    unsigned long long* buf = (unsigned long long*)hB;

    const int nb_l2 = (n + 255) / 256;   // 196
    const int nb_g  = (n + 15) / 16;     // 3125

    // CSR build (no global atomics, no memset)
    k_l1hist<<<nb_l1, 256, 0, stream>>>(idx, bh, E, etot);
    k_colscan<<<1, 256, 0, stream>>>(bh, base, goff, nb_l1);
    k_l1scatter<<<nb_l1, 256, 0, stream>>>(idx, base, buf, E, etot);
    k_l2build<<<nb_l2, 256, 0, stream>>>(buf, goff, off, csr, n, etot);

    // layer 0 GEMM: x(128) -> hA, logits A
    k_gemm_alpha<128, 4, 16><<<nb_g, 256, 0, stream>>>(x, W0, as0, ad0, hA, asbA, adbA, n);
    // agg0 (+b0, ELU) -> gemm1 -> hB, logits B
    k_agg_gemm<4, 4, 16><<<nb_g, 256, 0, stream>>>(hA, asbA, adbA, off, csr, b0,
                                                   W1, as1, ad1, hB, asbB, adbB, n);
    // agg1 (+b1, ELU) -> gemm2 -> hA, logits A
    k_agg_gemm<4, 1, 64><<<nb_g, 256, 0, stream>>>(hB, asbB, adbB, off, csr, b1,
                                                   W2, as2, ad2, hA, asbA, adbA, n);
    // agg2 (+b2) -> out
    k_agg_final<<<nb_g, 256, 0, stream>>>(hA, asbA, adbA, off, csr, b2, out, n);
}

// Round 11
// 292.817 us; speedup vs baseline: 1.1716x; 1.1716x over previous
//
#include <hip/hip_runtime.h>
#include <hip/hip_fp16.h>
#include <math.h>

// GAT 3-layer forward for MI355X.
// R10: (a) CSR build reverted to R8 form (R9's colscan was a 46us serial
// regression); (b) h activation tensors stored fp16 for the gather path
// (halves the 218MB/dispatch h-row traffic that pins agg at 58us). All
// arithmetic fp32; only the gathered h rows are fp16. Structure: 5 CSR
// dispatches, gemm0, [agg+gemm] x2 fused, agg_final.

#define NEG_SLOPE 0.2f
#define L1_CHUNK 4096

// ---------------- two-level CSR build (R8-validated) ----------------

__global__ __launch_bounds__(256) void k_l1hist(
    const int* __restrict__ idx, int* __restrict__ ghist, int E, int etot) {
    __shared__ int h[256];
    const int t = threadIdx.x;
    h[t] = 0;
    __syncthreads();
    const int base = blockIdx.x * L1_CHUNK;
    for (int i = t; i < L1_CHUNK; i += 256) {
        int e = base + i;
        if (e >= etot) break;
        int dst = (e < E) ? idx[E + e] : (e - E);
        atomicAdd(&h[dst >> 8], 1);
    }
    __syncthreads();
    if (h[t]) atomicAdd(&ghist[t], h[t]);
}

__global__ __launch_bounds__(256) void k_scan256(
    const int* __restrict__ ghist, int* __restrict__ goff, int* __restrict__ gcur) {
    __shared__ int sc[256];
    const int t = threadIdx.x;
    int v = ghist[t];
    sc[t] = v;
    __syncthreads();
    for (int o = 1; o < 256; o <<= 1) {
        int x = (t >= o) ? sc[t - o] : 0;
        __syncthreads();
        sc[t] += x;
        __syncthreads();
    }
    int excl = sc[t] - v;
    goff[t] = excl;
    gcur[t] = excl;
    if (t == 255) goff[256] = sc[255];
}

__global__ __launch_bounds__(256) void k_l1scatter(
    const int* __restrict__ idx, int* __restrict__ gcur,
    unsigned long long* __restrict__ buf, int E, int etot) {
    __shared__ int h[256];
    __shared__ int lbase[256];
    const int t = threadIdx.x;
    h[t] = 0;
    __syncthreads();
    const int base = blockIdx.x * L1_CHUNK;
    for (int i = t; i < L1_CHUNK; i += 256) {
        int e = base + i;
        if (e >= etot) break;
        int dst = (e < E) ? idx[E + e] : (e - E);
        atomicAdd(&h[dst >> 8], 1);
    }
    __syncthreads();
    lbase[t] = h[t] ? atomicAdd(&gcur[t], h[t]) : 0;
    __syncthreads();
    h[t] = lbase[t];
    __syncthreads();
    for (int i = t; i < L1_CHUNK; i += 256) {
        int e = base + i;
        if (e >= etot) break;
        int dst, src;
        if (e < E) { dst = idx[E + e]; src = idx[e]; }
        else       { dst = src = e - E; }
        int pos = atomicAdd(&h[dst >> 8], 1);
        buf[pos] = ((unsigned long long)(unsigned)dst << 32) | (unsigned)src;
    }
}

__global__ __launch_bounds__(256) void k_l2build(
    const unsigned long long* __restrict__ buf, const int* __restrict__ goff,
    int* __restrict__ off, int* __restrict__ csr, int n, int etot) {
    __shared__ int sc[256];
    __shared__ int lcur[256];
    const int b = blockIdx.x, t = threadIdx.x;
    const int lo = goff[b], hi = goff[b + 1];
    sc[t] = 0;
    __syncthreads();
    for (int p = lo + t; p < hi; p += 256) {
        int dst = (int)(buf[p] >> 32);
        atomicAdd(&sc[dst & 255], 1);
    }
    __syncthreads();
    int v = sc[t];
    __syncthreads();
    sc[t] = v;
    __syncthreads();
    for (int o = 1; o < 256; o <<= 1) {
        int x = (t >= o) ? sc[t - o] : 0;
        __syncthreads();
        sc[t] += x;
        __syncthreads();
    }
    int excl = sc[t] - v;
    const int d = b * 256 + t;
    if (d < n) off[d] = lo + excl;
    lcur[t] = lo + excl;
    __syncthreads();
    for (int p = lo + t; p < hi; p += 256) {
        unsigned long long e = buf[p];
        int dst = (int)(e >> 32);
        int src = (int)(e & 0xffffffffu);
        int pos = atomicAdd(&lcur[dst & 255], 1);
        csr[pos] = src;
    }
    if (b == 0 && t == 0) off[n] = etot;
}

// ---------------- compute ----------------

// Quarter-per-node aggregate over fp16 h rows. The calling quarter's 16
// lanes own all 64 cols of `node` (lane c4 -> cols 4c4..4c4+3, 8B load).
// Depth-2 software pipeline on the csr->asb/h chain; den is lane-local.
// Returns averaged fp32 result valid on all 16 lanes of the quarter.
template <int H>
__device__ __forceinline__ float4 aggq(
    const __half* __restrict__ h, const float* __restrict__ asb,
    const float* __restrict__ adb, const int* __restrict__ off,
    const int* __restrict__ csr, int node, int c4, int n) {
    const int head = (H == 1) ? 0 : (c4 >> 2);
    float den = 0.f;
    float4 acc = make_float4(0.f, 0.f, 0.f, 0.f);
    int p = 0, e = 0;
    float adn = 0.f;
    if (node < n) {
        p = off[node];
        e = off[node + 1];
        adn = adb[node * H + head];
    }
    int s0 = csr[p < e ? p : 0];
    int s1 = csr[(p + 1) < e ? (p + 1) : 0];
    float as0 = asb[s0 * H + head];
    uint2 hv0 = *(const uint2*)(h + (size_t)s0 * 64 + c4 * 4);
    while (__any(p < e)) {
        const bool valid = p < e;
        const int p2 = p + 2;
        const int s2 = csr[p2 < e ? p2 : 0];
        const float as1 = asb[s1 * H + head];
        const uint2 hv1 = *(const uint2*)(h + (size_t)s1 * 64 + c4 * 4);
        float ev = as0 + adn;
        ev = ev > 0.f ? ev : NEG_SLOPE * ev;
        const float wv = valid ? __expf(ev) : 0.f;
        const float2 f01 = __half22float2(*(const __half2*)&hv0.x);
        const float2 f23 = __half22float2(*(const __half2*)&hv0.y);
        den += wv;
        acc.x = fmaf(wv, f01.x, acc.x);
        acc.y = fmaf(wv, f01.y, acc.y);
        acc.z = fmaf(wv, f23.x, acc.z);
        acc.w = fmaf(wv, f23.y, acc.w);
        p = p + 1;
        s0 = s1; s1 = s2; as0 = as1; hv0 = hv1;
    }
    const float inv = 1.f / (den + 1e-16f);
    return make_float4(acc.x * inv, acc.y * inv, acc.z * inv, acc.w * inv);
}

// Layer-0 GEMM: h = x @ W (K=128) + logits. Block = 16 nodes, wave = 4.
// h written fp16; logits fp32 (from fp32 acc).
template <int K, int H, int F>
__global__ __launch_bounds__(256) void k_gemm_alpha(
    const float* __restrict__ x, const float* __restrict__ W,
    const float* __restrict__ a_s, const float* __restrict__ a_d,
    __half* __restrict__ h, float* __restrict__ as_o, float* __restrict__ ad_o,
    int n) {
    __shared__ float xs[16][K];
    const int tid = threadIdx.x;
    const int base = blockIdx.x * 16;
    int rows = n - base; if (rows > 16) rows = 16;
    const int kv = K / 4;
    for (int i = tid; i < rows * kv; i += 256) {
        int r = i / kv, c = i - r * kv;
        ((float4*)&xs[r][0])[c] = ((const float4*)(x + (size_t)(base + r) * K))[c];
    }
    __syncthreads();
    const int w = tid >> 6, lane = tid & 63;
    const int node0 = base + w * 4;
    float acc0 = 0.f, acc1 = 0.f, acc2 = 0.f, acc3 = 0.f;
    #pragma unroll 4
    for (int k = 0; k < K; ++k) {
        float wv = W[k * 64 + lane];
        acc0 = fmaf(xs[w * 4 + 0][k], wv, acc0);
        acc1 = fmaf(xs[w * 4 + 1][k], wv, acc1);
        acc2 = fmaf(xs[w * 4 + 2][k], wv, acc2);
        acc3 = fmaf(xs[w * 4 + 3][k], wv, acc3);
    }
    const int head = (H == 1) ? 0 : (lane >> 4);
    const int f = (H == 1) ? lane : (lane & (F - 1));
    const float asv = a_s[head * F + f];
    const float adv = a_d[head * F + f];
    float accs[4] = {acc0, acc1, acc2, acc3};
    #pragma unroll
    for (int j = 0; j < 4; ++j) {
        int node = node0 + j;
        if (node >= n) break;
        h[(size_t)node * 64 + lane] = __float2half_rn(accs[j]);
        float vs = accs[j] * asv;
        float vd = accs[j] * adv;
        #pragma unroll
        for (int o = F >> 1; o > 0; o >>= 1) {
            vs += __shfl_xor(vs, o);
            vd += __shfl_xor(vd, o);
        }
        if (f == 0) {
            as_o[node * H + head] = vs;
            ad_o[node * H + head] = vd;
        }
    }
}

// Fused agg(layer l) -> +bias -> ELU -> gemm(layer l+1) + logits.
// Quarter q of wave w aggregates node base + w*4 + q into LDS row w*4+q.
template <int HA, int HG, int FG>
__global__ __launch_bounds__(256) void k_agg_gemm(
    const __half* __restrict__ h_in, const float* __restrict__ asb_in,
    const float* __restrict__ adb_in, const int* __restrict__ off,
    const int* __restrict__ csr, const float* __restrict__ bias,
    const float* __restrict__ W, const float* __restrict__ a_s,
    const float* __restrict__ a_d, __half* __restrict__ h_out,
    float* __restrict__ asb_out, float* __restrict__ adb_out, int n) {
    __shared__ float xs[16][64];
    const int tid = threadIdx.x;
    const int w = tid >> 6, lane = tid & 63;
    const int q = lane >> 4, c4 = lane & 15;
    const int base = blockIdx.x * 16;
    const int nodeA = base + w * 4 + q;
    float4 r = aggq<HA>(h_in, asb_in, adb_in, off, csr, nodeA, c4, n);
    if (nodeA < n) {
        const float4 bv = *(const float4*)(bias + c4 * 4);
        r.x += bv.x; r.y += bv.y; r.z += bv.z; r.w += bv.w;
        r.x = r.x > 0.f ? r.x : expm1f(r.x);
        r.y = r.y > 0.f ? r.y : expm1f(r.y);
        r.z = r.z > 0.f ? r.z : expm1f(r.z);
        r.w = r.w > 0.f ? r.w : expm1f(r.w);
        *(float4*)&xs[w * 4 + q][c4 * 4] = r;
    }
    __syncthreads();
    float acc0 = 0.f, acc1 = 0.f, acc2 = 0.f, acc3 = 0.f;
    #pragma unroll 4
    for (int k = 0; k < 64; ++k) {
        float wv = W[k * 64 + lane];
        acc0 = fmaf(xs[w * 4 + 0][k], wv, acc0);
        acc1 = fmaf(xs[w * 4 + 1][k], wv, acc1);
        acc2 = fmaf(xs[w * 4 + 2][k], wv, acc2);
        acc3 = fmaf(xs[w * 4 + 3][k], wv, acc3);
    }
    const int head = (HG == 1) ? 0 : (lane >> 4);
    const int f = (HG == 1) ? lane : (lane & (FG - 1));
    const float asv = a_s[head * FG + f];
    const float adv = a_d[head * FG + f];
    float accs[4] = {acc0, acc1, acc2, acc3};
    const int node0 = base + w * 4;
    #pragma unroll
    for (int j = 0; j < 4; ++j) {
        int node = node0 + j;
        if (node >= n) break;
        h_out[(size_t)node * 64 + lane] = __float2half_rn(accs[j]);
        float vs = accs[j] * asv;
        float vd = accs[j] * adv;
        #pragma unroll
        for (int o = FG >> 1; o > 0; o >>= 1) {
            vs += __shfl_xor(vs, o);
            vd += __shfl_xor(vd, o);
        }
        if (f == 0) {
            asb_out[node * HG + head] = vs;
            adb_out[node * HG + head] = vd;
        }
    }
}

// Final aggregate (layer 2, H=1, no ELU) -> fp32 d_out. Quarter per node.
__global__ __launch_bounds__(256) void k_agg_final(
    const __half* __restrict__ h, const float* __restrict__ asb,
    const float* __restrict__ adb, const int* __restrict__ off,
    const int* __restrict__ csr, const float* __restrict__ bias,
    float* __restrict__ out, int n) {
    const int tid = threadIdx.x;
    const int w = tid >> 6, lane = tid & 63;
    const int q = lane >> 4, c4 = lane & 15;
    const int node = blockIdx.x * 16 + w * 4 + q;
    float4 r = aggq<1>(h, asb, adb, off, csr, node, c4, n);
    if (node < n) {
        const float4 bv = *(const float4*)(bias + c4 * 4);
        r.x += bv.x; r.y += bv.y; r.z += bv.z; r.w += bv.w;
        *(float4*)(out + (size_t)node * 64 + c4 * 4) = r;
    }
}

// ---------------- launch ----------------

extern "C" void kernel_launch(void* const* d_in, const int* in_sizes, int n_in,
                              void* d_out, int out_size, void* d_ws, size_t ws_size,
                              hipStream_t stream) {
    const float* x   = (const float*)d_in[0];
    const int*   idx = (const int*)d_in[1];
    const float* W0  = (const float*)d_in[2];
    const float* as0 = (const float*)d_in[3];
    const float* ad0 = (const float*)d_in[4];
    const float* b0  = (const float*)d_in[5];
    const float* W1  = (const float*)d_in[6];
    const float* as1 = (const float*)d_in[7];
    const float* ad1 = (const float*)d_in[8];
    const float* b1  = (const float*)d_in[9];
    const float* W2  = (const float*)d_in[10];
    const float* as2 = (const float*)d_in[11];
    const float* ad2 = (const float*)d_in[12];
    const float* b2  = (const float*)d_in[13];
    float* out = (float*)d_out;

    const int n    = in_sizes[0] / 128;   // 50000
    const int E    = in_sizes[1] / 2;     // 800000
    const int etot = E + n;

    char* p = (char*)d_ws;
    auto alloc = [&](size_t bytes) {
        char* r = p;
        p += (bytes + 255) & ~(size_t)255;
        return r;
    };
    int*    off   = (int*)alloc((size_t)(n + 1) * 4);
    int*    csr   = (int*)alloc((size_t)etot * 4);
    int*    ghist = (int*)alloc(256 * 4);
    int*    goff  = (int*)alloc(257 * 4);
    int*    gcur  = (int*)alloc(256 * 4);
    float*  asbA  = (float*)alloc((size_t)n * 4 * 4);
    float*  adbA  = (float*)alloc((size_t)n * 4 * 4);
    float*  asbB  = (float*)alloc((size_t)n * 4 * 4);
    float*  adbB  = (float*)alloc((size_t)n * 4 * 4);
    __half* hA    = (__half*)alloc((size_t)n * 64 * 2);
    __half* hB    = (__half*)alloc((size_t)n * 64 * 2);
    unsigned long long* buf = (unsigned long long*)alloc((size_t)etot * 8);

    const int nb_l1 = (etot + L1_CHUNK - 1) / L1_CHUNK;  // 208
    const int nb_l2 = (n + 255) / 256;                   // 196
    const int nb_g  = (n + 15) / 16;                     // 3125

    // CSR build (R8-validated form)
    hipMemsetAsync(ghist, 0, 256 * 4, stream);
    k_l1hist<<<nb_l1, 256, 0, stream>>>(idx, ghist, E, etot);
    k_scan256<<<1, 256, 0, stream>>>(ghist, goff, gcur);
    k_l1scatter<<<nb_l1, 256, 0, stream>>>(idx, gcur, buf, E, etot);
    k_l2build<<<nb_l2, 256, 0, stream>>>(buf, goff, off, csr, n, etot);

    // layer 0 GEMM: x(128) -> hA(fp16), logits A
    k_gemm_alpha<128, 4, 16><<<nb_g, 256, 0, stream>>>(x, W0, as0, ad0, hA, asbA, adbA, n);
    // agg0 (+b0, ELU) -> gemm1 -> hB(fp16), logits B
    k_agg_gemm<4, 4, 16><<<nb_g, 256, 0, stream>>>(hA, asbA, adbA, off, csr, b0,
                                                   W1, as1, ad1, hB, asbB, adbB, n);
    // agg1 (+b1, ELU) -> gemm2 -> hA(fp16), logits A
    k_agg_gemm<4, 1, 64><<<nb_g, 256, 0, stream>>>(hB, asbB, adbB, off, csr, b1,
                                                   W2, as2, ad2, hA, asbA, adbA, n);
    // agg2 (+b2) -> fp32 out
    k_agg_final<<<nb_g, 256, 0, stream>>>(hA, asbA, adbA, off, csr, b2, out, n);
}

// Round 12
// 258.458 us; speedup vs baseline: 1.3273x; 1.1329x over previous
//
#include <hip/hip_runtime.h>
#include <hip/hip_fp16.h>
#include <math.h>

// GAT 3-layer forward for MI355X.
// R11: agg edge-loop unrolled x2 with depth-4 prefetch pipeline (16 gather
// chains in flight per wave, 2x R10) and zero-padded csr (+8) so prefetch
// addresses need no per-stage clamping (p freezes when done). Everything
// else = R10: fp16 h gather arrays, fp32 math, two-level CSR build, gemm0,
// [agg+gemm] x2 fused, agg_final.

#define NEG_SLOPE 0.2f
#define L1_CHUNK 4096

// ---------------- two-level CSR build (R8-validated) ----------------

__global__ __launch_bounds__(256) void k_l1hist(
    const int* __restrict__ idx, int* __restrict__ ghist, int E, int etot) {
    __shared__ int h[256];
    const int t = threadIdx.x;
    h[t] = 0;
    __syncthreads();
    const int base = blockIdx.x * L1_CHUNK;
    for (int i = t; i < L1_CHUNK; i += 256) {
        int e = base + i;
        if (e >= etot) break;
        int dst = (e < E) ? idx[E + e] : (e - E);
        atomicAdd(&h[dst >> 8], 1);
    }
    __syncthreads();
    if (h[t]) atomicAdd(&ghist[t], h[t]);
}

__global__ __launch_bounds__(256) void k_scan256(
    const int* __restrict__ ghist, int* __restrict__ goff, int* __restrict__ gcur) {
    __shared__ int sc[256];
    const int t = threadIdx.x;
    int v = ghist[t];
    sc[t] = v;
    __syncthreads();
    for (int o = 1; o < 256; o <<= 1) {
        int x = (t >= o) ? sc[t - o] : 0;
        __syncthreads();
        sc[t] += x;
        __syncthreads();
    }
    int excl = sc[t] - v;
    goff[t] = excl;
    gcur[t] = excl;
    if (t == 255) goff[256] = sc[255];
}

__global__ __launch_bounds__(256) void k_l1scatter(
    const int* __restrict__ idx, int* __restrict__ gcur,
    unsigned long long* __restrict__ buf, int E, int etot) {
    __shared__ int h[256];
    __shared__ int lbase[256];
    const int t = threadIdx.x;
    h[t] = 0;
    __syncthreads();
    const int base = blockIdx.x * L1_CHUNK;
    for (int i = t; i < L1_CHUNK; i += 256) {
        int e = base + i;
        if (e >= etot) break;
        int dst = (e < E) ? idx[E + e] : (e - E);
        atomicAdd(&h[dst >> 8], 1);
    }
    __syncthreads();
    lbase[t] = h[t] ? atomicAdd(&gcur[t], h[t]) : 0;
    __syncthreads();
    h[t] = lbase[t];
    __syncthreads();
    for (int i = t; i < L1_CHUNK; i += 256) {
        int e = base + i;
        if (e >= etot) break;
        int dst, src;
        if (e < E) { dst = idx[E + e]; src = idx[e]; }
        else       { dst = src = e - E; }
        int pos = atomicAdd(&h[dst >> 8], 1);
        buf[pos] = ((unsigned long long)(unsigned)dst << 32) | (unsigned)src;
    }
}

__global__ __launch_bounds__(256) void k_l2build(
    const unsigned long long* __restrict__ buf, const int* __restrict__ goff,
    int* __restrict__ off, int* __restrict__ csr, int n, int etot) {
    __shared__ int sc[256];
    __shared__ int lcur[256];
    const int b = blockIdx.x, t = threadIdx.x;
    const int lo = goff[b], hi = goff[b + 1];
    sc[t] = 0;
    __syncthreads();
    for (int p = lo + t; p < hi; p += 256) {
        int dst = (int)(buf[p] >> 32);
        atomicAdd(&sc[dst & 255], 1);
    }
    __syncthreads();
    int v = sc[t];
    __syncthreads();
    sc[t] = v;
    __syncthreads();
    for (int o = 1; o < 256; o <<= 1) {
        int x = (t >= o) ? sc[t - o] : 0;
        __syncthreads();
        sc[t] += x;
        __syncthreads();
    }
    int excl = sc[t] - v;
    const int d = b * 256 + t;
    if (d < n) off[d] = lo + excl;
    lcur[t] = lo + excl;
    __syncthreads();
    for (int p = lo + t; p < hi; p += 256) {
        unsigned long long e = buf[p];
        int dst = (int)(e >> 32);
        int src = (int)(e & 0xffffffffu);
        int pos = atomicAdd(&lcur[dst & 255], 1);
        csr[pos] = src;
    }
    if (b == 0 && t == 0) off[n] = etot;
    if (b == 0 && t < 8) csr[etot + t] = 0;   // prefetch pad (safe src idx)
}

// ---------------- compute ----------------

// Quarter-per-node aggregate over fp16 h rows, unroll x2, depth-4 pipeline.
// 16 lanes own all 64 cols of `node` (lane c4 -> cols 4c4..4c4+3, 8B load).
// csr is zero-padded by 8 so stage loads need no clamp; p freezes at >=e.
// Returns averaged fp32 result valid on all 16 lanes of the quarter.
template <int H>
__device__ __forceinline__ float4 aggq(
    const __half* __restrict__ h, const float* __restrict__ asb,
    const float* __restrict__ adb, const int* __restrict__ off,
    const int* __restrict__ csr, int node, int c4, int n) {
    const int head = (H == 1) ? 0 : (c4 >> 2);
    float den = 0.f;
    float4 acc = make_float4(0.f, 0.f, 0.f, 0.f);
    int p = 0, e = 0;
    float adn = 0.f;
    if (node < n) {
        p = off[node];
        e = off[node + 1];
        adn = adb[node * H + head];
    }
    // prologue: stages p..p+3 (all reads in-bounds thanks to +8 pad)
    int s0 = csr[p], s1 = csr[p + 1], s2 = csr[p + 2], s3 = csr[p + 3];
    float a0 = asb[s0 * H + head];
    float a1 = asb[s1 * H + head];
    uint2 v0 = *(const uint2*)(h + (size_t)s0 * 64 + c4 * 4);
    uint2 v1 = *(const uint2*)(h + (size_t)s1 * 64 + c4 * 4);
    while (__any(p < e)) {
        const bool q0 = p < e;
        const bool q1 = (p + 1) < e;
        // issue stage p+4/p+5 loads (frozen p keeps these in-bounds)
        const int s4 = csr[p + 4];
        const int s5 = csr[p + 5];
        const float a2 = asb[s2 * H + head];
        const float a3 = asb[s3 * H + head];
        const uint2 v2 = *(const uint2*)(h + (size_t)s2 * 64 + c4 * 4);
        const uint2 v3 = *(const uint2*)(h + (size_t)s3 * 64 + c4 * 4);
        // consume edge p
        {
            float ev = a0 + adn;
            ev = ev > 0.f ? ev : NEG_SLOPE * ev;
            const float wv = q0 ? __expf(ev) : 0.f;
            const float2 f01 = __half22float2(*(const __half2*)&v0.x);
            const float2 f23 = __half22float2(*(const __half2*)&v0.y);
            den += wv;
            acc.x = fmaf(wv, f01.x, acc.x);
            acc.y = fmaf(wv, f01.y, acc.y);
            acc.z = fmaf(wv, f23.x, acc.z);
            acc.w = fmaf(wv, f23.y, acc.w);
        }
        // consume edge p+1
        {
            float ev = a1 + adn;
            ev = ev > 0.f ? ev : NEG_SLOPE * ev;
            const float wv = q1 ? __expf(ev) : 0.f;
            const float2 f01 = __half22float2(*(const __half2*)&v1.x);
            const float2 f23 = __half22float2(*(const __half2*)&v1.y);
            den += wv;
            acc.x = fmaf(wv, f01.x, acc.x);
            acc.y = fmaf(wv, f01.y, acc.y);
            acc.z = fmaf(wv, f23.x, acc.z);
            acc.w = fmaf(wv, f23.y, acc.w);
        }
        p = q0 ? p + 2 : p;   // freeze when done (keeps prefetch in-bounds)
        s0 = s2; s1 = s3; s2 = s4; s3 = s5;
        a0 = a2; a1 = a3;
        v0 = v2; v1 = v3;
    }
    const float inv = 1.f / (den + 1e-16f);
    return make_float4(acc.x * inv, acc.y * inv, acc.z * inv, acc.w * inv);
}

// Layer-0 GEMM: h = x @ W (K=128) + logits. Block = 16 nodes, wave = 4.
template <int K, int H, int F>
__global__ __launch_bounds__(256) void k_gemm_alpha(
    const float* __restrict__ x, const float* __restrict__ W,
    const float* __restrict__ a_s, const float* __restrict__ a_d,
    __half* __restrict__ h, float* __restrict__ as_o, float* __restrict__ ad_o,
    int n) {
    __shared__ float xs[16][K];
    const int tid = threadIdx.x;
    const int base = blockIdx.x * 16;
    int rows = n - base; if (rows > 16) rows = 16;
    const int kv = K / 4;
    for (int i = tid; i < rows * kv; i += 256) {
        int r = i / kv, c = i - r * kv;
        ((float4*)&xs[r][0])[c] = ((const float4*)(x + (size_t)(base + r) * K))[c];
    }
    __syncthreads();
    const int w = tid >> 6, lane = tid & 63;
    const int node0 = base + w * 4;
    float acc0 = 0.f, acc1 = 0.f, acc2 = 0.f, acc3 = 0.f;
    #pragma unroll 4
    for (int k = 0; k < K; ++k) {
        float wv = W[k * 64 + lane];
        acc0 = fmaf(xs[w * 4 + 0][k], wv, acc0);
        acc1 = fmaf(xs[w * 4 + 1][k], wv, acc1);
        acc2 = fmaf(xs[w * 4 + 2][k], wv, acc2);
        acc3 = fmaf(xs[w * 4 + 3][k], wv, acc3);
    }
    const int head = (H == 1) ? 0 : (lane >> 4);
    const int f = (H == 1) ? lane : (lane & (F - 1));
    const float asv = a_s[head * F + f];
    const float adv = a_d[head * F + f];
    float accs[4] = {acc0, acc1, acc2, acc3};
    #pragma unroll
    for (int j = 0; j < 4; ++j) {
        int node = node0 + j;
        if (node >= n) break;
        h[(size_t)node * 64 + lane] = __float2half_rn(accs[j]);
        float vs = accs[j] * asv;
        float vd = accs[j] * adv;
        #pragma unroll
        for (int o = F >> 1; o > 0; o >>= 1) {
            vs += __shfl_xor(vs, o);
            vd += __shfl_xor(vd, o);
        }
        if (f == 0) {
            as_o[node * H + head] = vs;
            ad_o[node * H + head] = vd;
        }
    }
}

// Fused agg(layer l) -> +bias -> ELU -> gemm(layer l+1) + logits.
// Quarter q of wave w aggregates node base + w*4 + q into LDS row w*4+q.
template <int HA, int HG, int FG>
__global__ __launch_bounds__(256) void k_agg_gemm(
    const __half* __restrict__ h_in, const float* __restrict__ asb_in,
    const float* __restrict__ adb_in, const int* __restrict__ off,
    const int* __restrict__ csr, const float* __restrict__ bias,
    const float* __restrict__ W, const float* __restrict__ a_s,
    const float* __restrict__ a_d, __half* __restrict__ h_out,
    float* __restrict__ asb_out, float* __restrict__ adb_out, int n) {
    __shared__ float xs[16][64];
    const int tid = threadIdx.x;
    const int w = tid >> 6, lane = tid & 63;
    const int q = lane >> 4, c4 = lane & 15;
    const int base = blockIdx.x * 16;
    const int nodeA = base + w * 4 + q;
    float4 r = aggq<HA>(h_in, asb_in, adb_in, off, csr, nodeA, c4, n);
    if (nodeA < n) {
        const float4 bv = *(const float4*)(bias + c4 * 4);
        r.x += bv.x; r.y += bv.y; r.z += bv.z; r.w += bv.w;
        r.x = r.x > 0.f ? r.x : expm1f(r.x);
        r.y = r.y > 0.f ? r.y : expm1f(r.y);
        r.z = r.z > 0.f ? r.z : expm1f(r.z);
        r.w = r.w > 0.f ? r.w : expm1f(r.w);
        *(float4*)&xs[w * 4 + q][c4 * 4] = r;
    }
    __syncthreads();
    float acc0 = 0.f, acc1 = 0.f, acc2 = 0.f, acc3 = 0.f;
    #pragma unroll 4
    for (int k = 0; k < 64; ++k) {
        float wv = W[k * 64 + lane];
        acc0 = fmaf(xs[w * 4 + 0][k], wv, acc0);
        acc1 = fmaf(xs[w * 4 + 1][k], wv, acc1);
        acc2 = fmaf(xs[w * 4 + 2][k], wv, acc2);
        acc3 = fmaf(xs[w * 4 + 3][k], wv, acc3);
    }
    const int head = (HG == 1) ? 0 : (lane >> 4);
    const int f = (HG == 1) ? lane : (lane & (FG - 1));
    const float asv = a_s[head * FG + f];
    const float adv = a_d[head * FG + f];
    float accs[4] = {acc0, acc1, acc2, acc3};
    const int node0 = base + w * 4;
    #pragma unroll
    for (int j = 0; j < 4; ++j) {
        int node = node0 + j;
        if (node >= n) break;
        h_out[(size_t)node * 64 + lane] = __float2half_rn(accs[j]);
        float vs = accs[j] * asv;
        float vd = accs[j] * adv;
        #pragma unroll
        for (int o = FG >> 1; o > 0; o >>= 1) {
            vs += __shfl_xor(vs, o);
            vd += __shfl_xor(vd, o);
        }
        if (f == 0) {
            asb_out[node * HG + head] = vs;
            adb_out[node * HG + head] = vd;
        }
    }
}

// Final aggregate (layer 2, H=1, no ELU) -> fp32 d_out. Quarter per node.
__global__ __launch_bounds__(256) void k_agg_final(
    const __half* __restrict__ h, const float* __restrict__ asb,
    const float* __restrict__ adb, const int* __restrict__ off,
    const int* __restrict__ csr, const float* __restrict__ bias,
    float* __restrict__ out, int n) {
    const int tid = threadIdx.x;
    const int w = tid >> 6, lane = tid & 63;
    const int q = lane >> 4, c4 = lane & 15;
    const int node = blockIdx.x * 16 + w * 4 + q;
    float4 r = aggq<1>(h, asb, adb, off, csr, node, c4, n);
    if (node < n) {
        const float4 bv = *(const float4*)(bias + c4 * 4);
        r.x += bv.x; r.y += bv.y; r.z += bv.z; r.w += bv.w;
        *(float4*)(out + (size_t)node * 64 + c4 * 4) = r;
    }
}

// ---------------- launch ----------------

extern "C" void kernel_launch(void* const* d_in, const int* in_sizes, int n_in,
                              void* d_out, int out_size, void* d_ws, size_t ws_size,
                              hipStream_t stream) {
    const float* x   = (const float*)d_in[0];
    const int*   idx = (const int*)d_in[1];
    const float* W0  = (const float*)d_in[2];
    const float* as0 = (const float*)d_in[3];
    const float* ad0 = (const float*)d_in[4];
    const float* b0  = (const float*)d_in[5];
    const float* W1  = (const float*)d_in[6];
    const float* as1 = (const float*)d_in[7];
    const float* ad1 = (const float*)d_in[8];
    const float* b1  = (const float*)d_in[9];
    const float* W2  = (const float*)d_in[10];
    const float* as2 = (const float*)d_in[11];
    const float* ad2 = (const float*)d_in[12];
    const float* b2  = (const float*)d_in[13];
    float* out = (float*)d_out;

    const int n    = in_sizes[0] / 128;   // 50000
    const int E    = in_sizes[1] / 2;     // 800000
    const int etot = E + n;

    char* p = (char*)d_ws;
    auto alloc = [&](size_t bytes) {
        char* r = p;
        p += (bytes + 255) & ~(size_t)255;
        return r;
    };
    int*    off   = (int*)alloc((size_t)(n + 1) * 4);
    int*    csr   = (int*)alloc((size_t)(etot + 8) * 4);   // +8 prefetch pad
    int*    ghist = (int*)alloc(256 * 4);
    int*    goff  = (int*)alloc(257 * 4);
    int*    gcur  = (int*)alloc(256 * 4);
    float*  asbA  = (float*)alloc((size_t)n * 4 * 4);
    float*  adbA  = (float*)alloc((size_t)n * 4 * 4);
    float*  asbB  = (float*)alloc((size_t)n * 4 * 4);
    float*  adbB  = (float*)alloc((size_t)n * 4 * 4);
    __half* hA    = (__half*)alloc((size_t)n * 64 * 2);
    __half* hB    = (__half*)alloc((size_t)n * 64 * 2);
    unsigned long long* buf = (unsigned long long*)alloc((size_t)etot * 8);

    const int nb_l1 = (etot + L1_CHUNK - 1) / L1_CHUNK;  // 208
    const int nb_l2 = (n + 255) / 256;                   // 196
    const int nb_g  = (n + 15) / 16;                     // 3125

    // CSR build (R8-validated form)
    hipMemsetAsync(ghist, 0, 256 * 4, stream);
    k_l1hist<<<nb_l1, 256, 0, stream>>>(idx, ghist, E, etot);
    k_scan256<<<1, 256, 0, stream>>>(ghist, goff, gcur);
    k_l1scatter<<<nb_l1, 256, 0, stream>>>(idx, gcur, buf, E, etot);
    k_l2build<<<nb_l2, 256, 0, stream>>>(buf, goff, off, csr, n, etot);

    // layer 0 GEMM: x(128) -> hA(fp16), logits A
    k_gemm_alpha<128, 4, 16><<<nb_g, 256, 0, stream>>>(x, W0, as0, ad0, hA, asbA, adbA, n);
    // agg0 (+b0, ELU) -> gemm1 -> hB(fp16), logits B
    k_agg_gemm<4, 4, 16><<<nb_g, 256, 0, stream>>>(hA, asbA, adbA, off, csr, b0,
                                                   W1, as1, ad1, hB, asbB, adbB, n);
    // agg1 (+b1, ELU) -> gemm2 -> hA(fp16), logits A
    k_agg_gemm<4, 1, 64><<<nb_g, 256, 0, stream>>>(hB, asbB, adbB, off, csr, b1,
                                                   W2, as2, ad2, hA, asbA, adbA, n);
    // agg2 (+b2) -> fp32 out
    k_agg_final<<<nb_g, 256, 0, stream>>>(hA, asbA, adbA, off, csr, b2, out, n);
}